// Round 2
// baseline (4381.228 us; speedup 1.0000x reference)
//
#include <hip/hip_runtime.h>
#include <hip/hip_bf16.h>

#define NEG 0.01f
#define BN_EPS 1e-5f

typedef __hip_bfloat16 bf16;

// ---------------- kernels ----------------

__global__ void zero_stats_k(float* s) {
    s[blockIdx.x * blockDim.x + threadIdx.x] = 0.f;
}

// stats slot layout: [sum(64), sumsq(64), mean(64), rstd(64)] = 256 floats
__global__ void finalize_k(float* stats, int slotA, int slotB, float inv_n) {
    int slot = (blockIdx.x == 0) ? slotA : slotB;
    float* s = stats + (size_t)slot * 256;
    int c = threadIdx.x;  // 64 threads
    float m = s[c] * inv_n;
    float v = s[64 + c] * inv_n - m * m;
    s[128 + c] = m;
    s[192 + c] = rsqrtf(v + BN_EPS);
}

// Gather-GEMM sparse conv. One wave per output row, lane = out channel (64).
// TIN = float (first layer) or bf16 (intermediates). Output bf16.
// If bn_m != null: input rows are BN-normalized + LeakyReLU'd on the fly.
// If stat != null: accumulate per-channel sum/sumsq of the fp32 output.
// Sentinel neighbor index == n_in -> skipped (zero row in reference).
template <int CIN, int K, typename TIN>
__global__ __launch_bounds__(256) void subm_conv(
    const TIN* __restrict__ fin, const int* __restrict__ nbr,
    const float* __restrict__ W, const float* __restrict__ bn_m,
    const float* __restrict__ bn_r, bf16* __restrict__ out,
    float* __restrict__ stat, int n_out, int n_in) {
    const int lane = threadIdx.x & 63;
    const int wave = blockIdx.x * (blockDim.x >> 6) + (threadIdx.x >> 6);
    const int nwaves = gridDim.x * (blockDim.x >> 6);

    float bm = 0.f, br = 1.f;
    if (bn_m != nullptr && lane < CIN) { bm = bn_m[lane]; br = bn_r[lane]; }

    float ssum = 0.f, ssq = 0.f;

    const int rpw = (n_out + nwaves - 1) / nwaves;
    int n0 = wave * rpw;
    int n1 = n0 + rpw; if (n1 > n_out) n1 = n_out;

    for (int n = n0; n < n1; ++n) {
        int idxv = n_in;
        if (lane < K) idxv = nbr[(size_t)lane * n_out + n];
        float acc = 0.f;
        for (int k = 0; k < K; ++k) {
            int idx = __shfl(idxv, k);
            if (idx >= n_in) continue;  // sentinel / missing neighbor
            float fv = 0.f;
            if (lane < CIN) {
                fv = (float)fin[(size_t)idx * CIN + lane];
                if (bn_m != nullptr) {
                    fv = (fv - bm) * br;
                    fv = fv > 0.f ? fv : NEG * fv;
                }
            }
            const float* wk = W + (size_t)k * CIN * 64 + lane;
            #pragma unroll 16
            for (int j = 0; j < CIN; ++j)
                acc = fmaf(__shfl(fv, j), wk[(size_t)j * 64], acc);
        }
        out[(size_t)n * 64 + lane] = __float2bfloat16(acc);
        ssum += acc;
        ssq += acc * acc;
    }
    if (stat != nullptr) {
        atomicAdd(&stat[lane], ssum);
        atomicAdd(&stat[64 + lane], ssq);
    }
}

// out = bnact(a; ma,ra) + bnact(b; mb,rb)   (bf16 in, bf16 out)
__global__ void bn2_add(const bf16* __restrict__ a, const float* __restrict__ ma,
                        const float* __restrict__ ra, const bf16* __restrict__ b,
                        const float* __restrict__ mb, const float* __restrict__ rb,
                        bf16* __restrict__ out, int n_elem) {
    int i = blockIdx.x * blockDim.x + threadIdx.x;
    if (i >= n_elem) return;
    int c = i & 63;
    float va = ((float)a[i] - ma[c]) * ra[c];
    va = va > 0.f ? va : NEG * va;
    float vb = ((float)b[i] - mb[c]) * rb[c];
    vb = vb > 0.f ? vb : NEG * vb;
    out[i] = __float2bfloat16(va + vb);
}

// out[n,:] (+)= x[n,:] @ W(64x64). Wave per row, lane = out col.
__global__ __launch_bounds__(256) void down_part(
    const bf16* __restrict__ x, const float* __restrict__ W,
    float* __restrict__ out, int m, int accum) {
    const int lane = threadIdx.x & 63;
    const int wave = blockIdx.x * (blockDim.x >> 6) + (threadIdx.x >> 6);
    const int nwaves = gridDim.x * (blockDim.x >> 6);
    const int rpw = (m + nwaves - 1) / nwaves;
    int n0 = wave * rpw;
    int n1 = n0 + rpw; if (n1 > m) n1 = m;
    for (int n = n0; n < n1; ++n) {
        float v = (float)x[(size_t)n * 64 + lane];
        float acc = accum ? out[(size_t)n * 64 + lane] : 0.f;
        const float* w = W + lane;
        #pragma unroll 16
        for (int j = 0; j < 64; ++j)
            acc = fmaf(__shfl(v, j), w[(size_t)j * 64], acc);
        out[(size_t)n * 64 + lane] = acc;
    }
}

// ---------------- host ----------------

static const int GRID = 2048, BLK = 256;

extern "C" void kernel_launch(void* const* d_in, const int* in_sizes, int n_in,
                              void* d_out, int out_size, void* d_ws,
                              size_t ws_size, hipStream_t stream) {
    const float* feats  = (const float*)d_in[0];
    const float* b1_w1  = (const float*)d_in[1];
    const float* b1_w12 = (const float*)d_in[2];
    const float* b1_w2  = (const float*)d_in[3];
    const float* b1_w22 = (const float*)d_in[4];
    const float* pool_w = (const float*)d_in[5];
    const float* b2_w1  = (const float*)d_in[6];
    const float* b2_w12 = (const float*)d_in[7];
    const float* b2_w2  = (const float*)d_in[8];
    const float* b2_w22 = (const float*)d_in[9];
    const float* b3_w1  = (const float*)d_in[10];
    const float* b3_w12 = (const float*)d_in[11];
    const float* b3_w2  = (const float*)d_in[12];
    const float* b3_w22 = (const float*)d_in[13];
    const float* down_w = (const float*)d_in[14];
    const int* nA1  = (const int*)d_in[15];  // nbr331_d1 (9, N)
    const int* nB1  = (const int*)d_in[16];  // nbr313_d1 (9, N)
    const int* pnbr = (const int*)d_in[17];  // pool_nbr (27, M)
    const int* nA2  = (const int*)d_in[18];
    const int* nB2  = (const int*)d_in[19];
    const int* nA3  = (const int*)d_in[20];
    const int* nB3  = (const int*)d_in[21];

    const int N = in_sizes[0] / 32;   // 80000
    const int M = in_sizes[17] / 27;  // pooled active sites (can exceed N!)
    const size_t MX = (size_t)(N > M ? N : M);

    // workspace: 3 rotating bf16 feature buffers (MX x 64) + fp32 stats
    bf16* B0 = (bf16*)d_ws;
    bf16* B1 = B0 + MX * 64;
    bf16* B2 = B1 + MX * 64;
    float* ST = (float*)(B2 + MX * 64);  // 12 slots x 256 floats

    float* out = (float*)d_out;

    zero_stats_k<<<12, 256, 0, stream>>>(ST);
    auto S = [&](int i) { return ST + (size_t)i * 256; };

    const float invN = 1.f / (float)N, invM = 1.f / (float)M;
    const int neN = N * 64, neM = M * 64;

    // ---- block 1 @ N voxels, C 32->64 ----
    subm_conv<32, 9, float><<<GRID, BLK, 0, stream>>>(feats, nA1, b1_w1, nullptr, nullptr, B0, S(0), N, N);
    subm_conv<32, 9, float><<<GRID, BLK, 0, stream>>>(feats, nB1, b1_w2, nullptr, nullptr, B1, S(2), N, N);
    finalize_k<<<2, 64, 0, stream>>>(ST, 0, 2, invN);
    subm_conv<64, 9, bf16><<<GRID, BLK, 0, stream>>>(B0, nB1, b1_w12, S(0) + 128, S(0) + 192, B2, S(1), N, N);
    subm_conv<64, 9, bf16><<<GRID, BLK, 0, stream>>>(B1, nA1, b1_w22, S(2) + 128, S(2) + 192, B0, S(3), N, N);
    finalize_k<<<2, 64, 0, stream>>>(ST, 1, 3, invN);
    bn2_add<<<(neN + 255) / 256, 256, 0, stream>>>(B2, S(1) + 128, S(1) + 192, B0, S(3) + 128, S(3) + 192, B1, neN);
    // XP (x1 pre-pool) = B1

    // ---- strided pool conv, K=27: B1 (N,64) -> B2 (M,64) = X1 ----
    subm_conv<64, 27, bf16><<<GRID, BLK, 0, stream>>>(B1, pnbr, pool_w, nullptr, nullptr, B2, nullptr, M, N);
    down_part<<<GRID, BLK, 0, stream>>>(B2, down_w, out, M, 0);  // out = X1 @ W[0:64]

    // ---- block 2 @ M, dilation 2 (fin = B2) ----
    subm_conv<64, 9, bf16><<<GRID, BLK, 0, stream>>>(B2, nA2, b2_w1, nullptr, nullptr, B0, S(4), M, M);
    subm_conv<64, 9, bf16><<<GRID, BLK, 0, stream>>>(B2, nB2, b2_w2, nullptr, nullptr, B1, S(6), M, M);
    finalize_k<<<2, 64, 0, stream>>>(ST, 4, 6, invM);
    subm_conv<64, 9, bf16><<<GRID, BLK, 0, stream>>>(B0, nB2, b2_w12, S(4) + 128, S(4) + 192, B2, S(5), M, M);
    subm_conv<64, 9, bf16><<<GRID, BLK, 0, stream>>>(B1, nA2, b2_w22, S(6) + 128, S(6) + 192, B0, S(7), M, M);
    finalize_k<<<2, 64, 0, stream>>>(ST, 5, 7, invM);
    bn2_add<<<(neM + 255) / 256, 256, 0, stream>>>(B2, S(5) + 128, S(5) + 192, B0, S(7) + 128, S(7) + 192, B1, neM);
    // X2 = B1
    down_part<<<GRID, BLK, 0, stream>>>(B1, down_w + 64 * 64, out, M, 1);  // out += X2 @ W[64:128]

    // ---- block 3 @ M, dilation 3 (fin = B1) ----
    subm_conv<64, 9, bf16><<<GRID, BLK, 0, stream>>>(B1, nA3, b3_w1, nullptr, nullptr, B0, S(8), M, M);
    subm_conv<64, 9, bf16><<<GRID, BLK, 0, stream>>>(B1, nB3, b3_w2, nullptr, nullptr, B2, S(10), M, M);
    finalize_k<<<2, 64, 0, stream>>>(ST, 8, 10, invM);
    subm_conv<64, 9, bf16><<<GRID, BLK, 0, stream>>>(B0, nB3, b3_w12, S(8) + 128, S(8) + 192, B1, S(9), M, M);
    subm_conv<64, 9, bf16><<<GRID, BLK, 0, stream>>>(B2, nA3, b3_w22, S(10) + 128, S(10) + 192, B0, S(11), M, M);
    finalize_k<<<2, 64, 0, stream>>>(ST, 9, 11, invM);
    bn2_add<<<(neM + 255) / 256, 256, 0, stream>>>(B1, S(9) + 128, S(9) + 192, B0, S(11) + 128, S(11) + 192, B2, neM);
    // X3 = B2
    down_part<<<GRID, BLK, 0, stream>>>(B2, down_w + 128 * 64, out, M, 1);  // out += X3 @ W[128:192]
}